// Round 1
// baseline (68.906 us; speedup 1.0000x reference)
//
#include <hip/hip_runtime.h>

// Problem constants (match reference setup)
#define NXD   512
#define NYD   512
#define CD    64
#define BD    4
#define GRIDC (NXD * NYD)        // 262144 cells per frame (NZ==1)

// One thread per pillar: scatter occupancy / density / points_number.
__global__ void scatter_meta_kernel(const int* __restrict__ coords,
                                    const int* __restrict__ npts,
                                    float* __restrict__ occ,
                                    float* __restrict__ dens,
                                    float* __restrict__ pnum,
                                    int M) {
    int i = blockIdx.x * blockDim.x + threadIdx.x;
    if (i >= M) return;
    int b = coords[4 * i + 0];
    int z = coords[4 * i + 1];
    int y = coords[4 * i + 2];
    int x = coords[4 * i + 3];
    int cell = b * GRIDC + z + y * NXD + x;   // z==0 in this problem
    float n = (float)npts[i];
    occ[cell]  = 1.0f;
    dens[cell] = n * (1.0f / 32.0f);
    pnum[cell] = n;                           // integer <=32, exact in f32
}

// One 64-lane group per selected pillar; lane = channel.
// Feature-row read is coalesced (256B); writes are channel-strided (scatter).
__global__ void scatter_spatial_kernel(const float* __restrict__ feats,
                                       const int* __restrict__ coords,
                                       const int* __restrict__ sel,
                                       float* __restrict__ spatial,
                                       int K) {
    int group = blockIdx.x * (blockDim.x >> 6) + (threadIdx.x >> 6);
    int c     = threadIdx.x & 63;
    if (group >= K) return;
    int row = sel[group];
    int b = coords[4 * row + 0];
    int z = coords[4 * row + 1];
    int y = coords[4 * row + 2];
    int x = coords[4 * row + 3];
    int cell = z + y * NXD + x;
    float v = feats[(size_t)row * CD + c];
    spatial[(size_t)b * ((size_t)CD * GRIDC) + (size_t)c * GRIDC + (size_t)cell] = v;
}

extern "C" void kernel_launch(void* const* d_in, const int* in_sizes, int n_in,
                              void* d_out, int out_size, void* d_ws, size_t ws_size,
                              hipStream_t stream) {
    const float* feats  = (const float*)d_in[0];  // [M, 64] f32
    const int*   coords = (const int*)d_in[1];    // [M, 4]  (b,z,y,x)
    const int*   npts   = (const int*)d_in[2];    // [M]
    const int*   sel    = (const int*)d_in[3];    // [K]

    int M = in_sizes[2];
    int K = in_sizes[3];

    float* out = (float*)d_out;
    size_t spatial_elems = (size_t)BD * CD * GRIDC;   // 67,108,864
    size_t map_elems     = (size_t)BD * GRIDC;        //  1,048,576
    float* occ  = out + spatial_elems;
    float* dens = occ + map_elems;
    float* pnum = dens + map_elems;

    // Reference zeros everything not scattered; harness poisons d_out once.
    hipMemsetAsync(d_out, 0, (size_t)out_size * sizeof(float), stream);

    scatter_meta_kernel<<<(M + 255) / 256, 256, 0, stream>>>(
        coords, npts, occ, dens, pnum, M);

    // 4 pillars per 256-thread block
    scatter_spatial_kernel<<<(K + 3) / 4, 256, 0, stream>>>(
        feats, coords, sel, out, K);
}

// Round 3
// 68.849 us; speedup vs baseline: 1.0008x; 1.0008x over previous
//
#include <hip/hip_runtime.h>

#define NXD   512
#define NYD   512
#define CD    64
#define BD    4
#define GRIDC (NXD * NYD)          // 262144 cells per frame (NZ==1)
#define SEL_FLAG (1 << 20)         // row+1 <= 65536 < 1<<20

typedef float f32x4 __attribute__((ext_vector_type(4)));
typedef int   i32x4 __attribute__((ext_vector_type(4)));

// ---------------- fused path ----------------

// map[cell] = (row+1) | (selected ? SEL_FLAG : 0); 0 = empty.
// atomicOr so the row write and the flag write compose in any order.
__global__ void build_map_kernel(const int* __restrict__ coords,
                                 const int* __restrict__ sel,
                                 int* __restrict__ map, int M, int K) {
    int i = blockIdx.x * blockDim.x + threadIdx.x;
    if (i < M) {
        int b = coords[4 * i + 0];
        int z = coords[4 * i + 1];
        int y = coords[4 * i + 2];
        int x = coords[4 * i + 3];
        int cell = b * GRIDC + z + y * NXD + x;
        atomicOr(map + cell, i + 1);
    } else if (i < M + K) {
        int r = sel[i - M];
        int b = coords[4 * r + 0];
        int z = coords[4 * r + 1];
        int y = coords[4 * r + 2];
        int x = coords[4 * r + 3];
        int cell = b * GRIDC + z + y * NXD + x;
        atomicOr(map + cell, SEL_FLAG);
    }
}

// One pass writes EVERY output element exactly once (no prior memset of d_out).
// Block = 256 threads handles 1024 consecutive cells (within one frame:
// GRIDC % 1024 == 0). Thread owns 4 consecutive cells -> f32x4 stores.
__global__ __launch_bounds__(256) void fused_fill_kernel(
        const float* __restrict__ feats,
        const int*   __restrict__ npts,
        const int*   __restrict__ map,
        float* __restrict__ out) {
    const size_t base = (size_t)blockIdx.x * 1024;     // global cell id
    const int b   = (int)(base >> 18);                 // / GRIDC
    const int cif = (int)(base & (GRIDC - 1));         // cell within frame
    const int t   = threadIdx.x;
    const size_t cbase = base + (size_t)t * 4;

    // 4 map entries for this thread's cells (coalesced 16B load)
    const i32x4 m4 = *reinterpret_cast<const i32x4*>(map + cbase);
    int rows[4] = {m4.x, m4.y, m4.z, m4.w};

    // spatial: [B][64][GRIDC]
    float* __restrict__ spatial = out;
    const size_t sp_off = (size_t)b * ((size_t)CD * GRIDC) + (size_t)(cif + t * 4);

    #pragma unroll 4
    for (int c = 0; c < CD; ++c) {
        f32x4 v = (f32x4)(0.f);
        #pragma unroll
        for (int j = 0; j < 4; ++j) {
            int m = rows[j];
            if (m & SEL_FLAG)
                v[j] = feats[(size_t)((m & 0xFFFFF) - 1) * CD + c];
        }
        __builtin_nontemporal_store(
            v, reinterpret_cast<f32x4*>(spatial + sp_off + (size_t)c * GRIDC));
    }

    // meta maps: occ / dens / pnum, each [B][GRIDC]
    const size_t spatial_elems = (size_t)BD * CD * GRIDC;
    const size_t map_elems     = (size_t)BD * GRIDC;
    float* __restrict__ occ  = out + spatial_elems;
    float* __restrict__ dens = occ + map_elems;
    float* __restrict__ pnum = dens + map_elems;

    f32x4 o, d, p;
    #pragma unroll
    for (int j = 0; j < 4; ++j) {
        int m = rows[j];
        if (m != 0) {
            int row = (m & 0xFFFFF) - 1;
            float n = (float)npts[row];
            o[j] = 1.0f;
            d[j] = n * (1.0f / 32.0f);
            p[j] = n;
        } else {
            o[j] = 0.f; d[j] = 0.f; p[j] = 0.f;
        }
    }
    __builtin_nontemporal_store(o, reinterpret_cast<f32x4*>(occ  + cbase));
    __builtin_nontemporal_store(d, reinterpret_cast<f32x4*>(dens + cbase));
    __builtin_nontemporal_store(p, reinterpret_cast<f32x4*>(pnum + cbase));
}

// ---------------- fallback path (round-1, used if ws too small) ----------------

__global__ void scatter_meta_kernel(const int* __restrict__ coords,
                                    const int* __restrict__ npts,
                                    float* __restrict__ occ,
                                    float* __restrict__ dens,
                                    float* __restrict__ pnum,
                                    int M) {
    int i = blockIdx.x * blockDim.x + threadIdx.x;
    if (i >= M) return;
    int b = coords[4 * i + 0];
    int z = coords[4 * i + 1];
    int y = coords[4 * i + 2];
    int x = coords[4 * i + 3];
    int cell = b * GRIDC + z + y * NXD + x;
    float n = (float)npts[i];
    occ[cell]  = 1.0f;
    dens[cell] = n * (1.0f / 32.0f);
    pnum[cell] = n;
}

__global__ void scatter_spatial_kernel(const float* __restrict__ feats,
                                       const int* __restrict__ coords,
                                       const int* __restrict__ sel,
                                       float* __restrict__ spatial,
                                       int K) {
    int group = blockIdx.x * (blockDim.x >> 6) + (threadIdx.x >> 6);
    int c     = threadIdx.x & 63;
    if (group >= K) return;
    int row = sel[group];
    int b = coords[4 * row + 0];
    int z = coords[4 * row + 1];
    int y = coords[4 * row + 2];
    int x = coords[4 * row + 3];
    int cell = z + y * NXD + x;
    float v = feats[(size_t)row * CD + c];
    spatial[(size_t)b * ((size_t)CD * GRIDC) + (size_t)c * GRIDC + (size_t)cell] = v;
}

extern "C" void kernel_launch(void* const* d_in, const int* in_sizes, int n_in,
                              void* d_out, int out_size, void* d_ws, size_t ws_size,
                              hipStream_t stream) {
    const float* feats  = (const float*)d_in[0];  // [M, 64] f32
    const int*   coords = (const int*)d_in[1];    // [M, 4]  (b,z,y,x)
    const int*   npts   = (const int*)d_in[2];    // [M]
    const int*   sel    = (const int*)d_in[3];    // [K]

    const int M = in_sizes[2];
    const int K = in_sizes[3];

    float* out = (float*)d_out;
    const size_t map_bytes = (size_t)BD * GRIDC * sizeof(int);   // 4 MB

    if (ws_size >= map_bytes) {
        int* map = (int*)d_ws;
        (void)hipMemsetAsync(map, 0, map_bytes, stream);
        build_map_kernel<<<(M + K + 255) / 256, 256, 0, stream>>>(
            coords, sel, map, M, K);
        // 1,048,576 cells / 1024 per block
        fused_fill_kernel<<<(BD * GRIDC) / 1024, 256, 0, stream>>>(
            feats, npts, map, out);
    } else {
        // fallback: memset + scatter (round-1 path)
        size_t spatial_elems = (size_t)BD * CD * GRIDC;
        size_t map_elems     = (size_t)BD * GRIDC;
        float* occ  = out + spatial_elems;
        float* dens = occ + map_elems;
        float* pnum = dens + map_elems;
        (void)hipMemsetAsync(d_out, 0, (size_t)out_size * sizeof(float), stream);
        scatter_meta_kernel<<<(M + 255) / 256, 256, 0, stream>>>(
            coords, npts, occ, dens, pnum, M);
        scatter_spatial_kernel<<<(K + 3) / 4, 256, 0, stream>>>(
            feats, coords, sel, out, K);
    }
}

// Round 4
// 66.489 us; speedup vs baseline: 1.0363x; 1.0355x over previous
//
#include <hip/hip_runtime.h>

#define NXD   512
#define NYD   512
#define CD    64
#define BD    4
#define GRIDC (NXD * NYD)          // 262144 cells per frame (NZ==1)

// map encoding: bits[0:16] = row+1 (<=65536), bits[17:22] = npts (<=32), bit23 = selected
#define ROW_MASK   0x1FFFF
#define NPTS_SHIFT 17
#define SEL_FLAG   (1 << 23)

typedef float f32x4 __attribute__((ext_vector_type(4)));
typedef int   i32x4 __attribute__((ext_vector_type(4)));

// ---------------- fused path ----------------

// atomicOr so the pillar write and the selected-flag write compose in any order.
__global__ void build_map_kernel(const int* __restrict__ coords,
                                 const int* __restrict__ sel,
                                 const int* __restrict__ npts,
                                 int* __restrict__ map, int M, int K) {
    int i = blockIdx.x * blockDim.x + threadIdx.x;
    if (i < M) {
        int b = coords[4 * i + 0];
        int z = coords[4 * i + 1];
        int y = coords[4 * i + 2];
        int x = coords[4 * i + 3];
        int cell = b * GRIDC + z + y * NXD + x;
        atomicOr(map + cell, (i + 1) | (npts[i] << NPTS_SHIFT));
    } else if (i < M + K) {
        int r = sel[i - M];
        int b = coords[4 * r + 0];
        int z = coords[4 * r + 1];
        int y = coords[4 * r + 2];
        int x = coords[4 * r + 3];
        int cell = b * GRIDC + z + y * NXD + x;
        atomicOr(map + cell, SEL_FLAG);
    }
}

// One pass writes EVERY output element exactly once. Block = 256 threads
// handles 1024 consecutive cells of one frame; thread owns 4 cells.
// Branch-free gather: unselected cells read from a shared 256B zero buffer.
__global__ __launch_bounds__(256) void fused_fill_kernel(
        const float* __restrict__ feats,
        const int*   __restrict__ map,
        const float* __restrict__ zerobuf,
        float* __restrict__ out) {
    const size_t base = (size_t)blockIdx.x * 1024;     // global cell id
    const int b   = (int)(base >> 18);                 // / GRIDC
    const int cif = (int)(base & (GRIDC - 1));         // cell within frame
    const int t   = threadIdx.x;
    const size_t cbase = base + (size_t)t * 4;

    const i32x4 m4 = *reinterpret_cast<const i32x4*>(map + cbase);
    const int rows[4] = {m4.x, m4.y, m4.z, m4.w};

    // per-cell feature row pointer (or zero page) — computed once, branch-free loop
    const float* p[4];
    #pragma unroll
    for (int j = 0; j < 4; ++j) {
        int m = rows[j];
        p[j] = (m & SEL_FLAG) ? (feats + ((size_t)((m & ROW_MASK) - 1) << 6))
                              : zerobuf;
    }

    float* __restrict__ spatial = out;
    const size_t sp_off = (size_t)b * ((size_t)CD * GRIDC) + (size_t)(cif + t * 4);

    // 16 channel-groups of 4: vector-load 4 channels per cell, 4x4 register
    // transpose, 4 NT vector stores (one per channel).
    #pragma unroll 2
    for (int cg = 0; cg < 16; ++cg) {
        f32x4 f0 = *reinterpret_cast<const f32x4*>(p[0] + 4 * cg);
        f32x4 f1 = *reinterpret_cast<const f32x4*>(p[1] + 4 * cg);
        f32x4 f2 = *reinterpret_cast<const f32x4*>(p[2] + 4 * cg);
        f32x4 f3 = *reinterpret_cast<const f32x4*>(p[3] + 4 * cg);
        #pragma unroll
        for (int q = 0; q < 4; ++q) {
            f32x4 v;
            v[0] = f0[q]; v[1] = f1[q]; v[2] = f2[q]; v[3] = f3[q];
            __builtin_nontemporal_store(
                v, reinterpret_cast<f32x4*>(spatial + sp_off + (size_t)(4 * cg + q) * GRIDC));
        }
    }

    // meta maps: occ / dens / pnum, each [B][GRIDC]; npts decoded from map bits
    const size_t spatial_elems = (size_t)BD * CD * GRIDC;
    const size_t map_elems     = (size_t)BD * GRIDC;
    float* __restrict__ occ  = out + spatial_elems;
    float* __restrict__ dens = occ + map_elems;
    float* __restrict__ pnum = dens + map_elems;

    f32x4 o, d, pn;
    #pragma unroll
    for (int j = 0; j < 4; ++j) {
        int m = rows[j];
        if (m != 0) {
            float n = (float)((m >> NPTS_SHIFT) & 63);
            o[j] = 1.0f;
            d[j] = n * (1.0f / 32.0f);
            pn[j] = n;
        } else {
            o[j] = 0.f; d[j] = 0.f; pn[j] = 0.f;
        }
    }
    __builtin_nontemporal_store(o,  reinterpret_cast<f32x4*>(occ  + cbase));
    __builtin_nontemporal_store(d,  reinterpret_cast<f32x4*>(dens + cbase));
    __builtin_nontemporal_store(pn, reinterpret_cast<f32x4*>(pnum + cbase));
}

// ---------------- fallback path (used only if ws too small) ----------------

__global__ void scatter_meta_kernel(const int* __restrict__ coords,
                                    const int* __restrict__ npts,
                                    float* __restrict__ occ,
                                    float* __restrict__ dens,
                                    float* __restrict__ pnum,
                                    int M) {
    int i = blockIdx.x * blockDim.x + threadIdx.x;
    if (i >= M) return;
    int b = coords[4 * i + 0];
    int z = coords[4 * i + 1];
    int y = coords[4 * i + 2];
    int x = coords[4 * i + 3];
    int cell = b * GRIDC + z + y * NXD + x;
    float n = (float)npts[i];
    occ[cell]  = 1.0f;
    dens[cell] = n * (1.0f / 32.0f);
    pnum[cell] = n;
}

__global__ void scatter_spatial_kernel(const float* __restrict__ feats,
                                       const int* __restrict__ coords,
                                       const int* __restrict__ sel,
                                       float* __restrict__ spatial,
                                       int K) {
    int group = blockIdx.x * (blockDim.x >> 6) + (threadIdx.x >> 6);
    int c     = threadIdx.x & 63;
    if (group >= K) return;
    int row = sel[group];
    int b = coords[4 * row + 0];
    int z = coords[4 * row + 1];
    int y = coords[4 * row + 2];
    int x = coords[4 * row + 3];
    int cell = z + y * NXD + x;
    float v = feats[(size_t)row * CD + c];
    spatial[(size_t)b * ((size_t)CD * GRIDC) + (size_t)c * GRIDC + (size_t)cell] = v;
}

extern "C" void kernel_launch(void* const* d_in, const int* in_sizes, int n_in,
                              void* d_out, int out_size, void* d_ws, size_t ws_size,
                              hipStream_t stream) {
    const float* feats  = (const float*)d_in[0];  // [M, 64] f32
    const int*   coords = (const int*)d_in[1];    // [M, 4]  (b,z,y,x)
    const int*   npts   = (const int*)d_in[2];    // [M]
    const int*   sel    = (const int*)d_in[3];    // [K]

    const int M = in_sizes[2];
    const int K = in_sizes[3];

    float* out = (float*)d_out;
    const size_t map_bytes = (size_t)BD * GRIDC * sizeof(int);   // 4 MB
    const size_t zero_bytes = CD * sizeof(float);                // 256 B

    if (ws_size >= map_bytes + zero_bytes) {
        int* map = (int*)d_ws;
        const float* zerobuf = (const float*)((char*)d_ws + map_bytes);
        (void)hipMemsetAsync(d_ws, 0, map_bytes + zero_bytes, stream);
        build_map_kernel<<<(M + K + 255) / 256, 256, 0, stream>>>(
            coords, sel, npts, map, M, K);
        fused_fill_kernel<<<(BD * GRIDC) / 1024, 256, 0, stream>>>(
            feats, map, zerobuf, out);
    } else {
        // fallback: memset + scatter
        size_t spatial_elems = (size_t)BD * CD * GRIDC;
        size_t map_elems     = (size_t)BD * GRIDC;
        float* occ  = out + spatial_elems;
        float* dens = occ + map_elems;
        float* pnum = dens + map_elems;
        (void)hipMemsetAsync(d_out, 0, (size_t)out_size * sizeof(float), stream);
        scatter_meta_kernel<<<(M + 255) / 256, 256, 0, stream>>>(
            coords, npts, occ, dens, pnum, M);
        scatter_spatial_kernel<<<(K + 3) / 4, 256, 0, stream>>>(
            feats, coords, sel, out, K);
    }
}

// Round 5
// 57.763 us; speedup vs baseline: 1.1929x; 1.1511x over previous
//
#include <hip/hip_runtime.h>

#define NXD   512
#define NYD   512
#define CD    64
#define BD    4
#define GRIDC (NXD * NYD)          // 262144 cells per frame (NZ==1)

// map encoding: bits[0:16] = row+1 (<=65536), bits[17:22] = npts (<=32), bit23 = selected
#define ROW_MASK   0x1FFFF
#define NPTS_SHIFT 17
#define SEL_FLAG   (1 << 23)

#define CHUNKS_PER_PLANE (GRIDC / 1024)                  // 256
#define SPATIAL_BLOCKS   (BD * CD * CHUNKS_PER_PLANE)    // 65536
#define META_BLOCKS      (BD * GRIDC / 1024)             // 1024

typedef float f32x4 __attribute__((ext_vector_type(4)));
typedef int   i32x4 __attribute__((ext_vector_type(4)));

// ---------------- fused path ----------------

// atomicOr so the pillar write and the selected-flag write compose in any order.
__global__ void build_map_kernel(const int* __restrict__ coords,
                                 const int* __restrict__ sel,
                                 const int* __restrict__ npts,
                                 int* __restrict__ map, int M, int K) {
    int i = blockIdx.x * blockDim.x + threadIdx.x;
    if (i < M) {
        int b = coords[4 * i + 0];
        int z = coords[4 * i + 1];
        int y = coords[4 * i + 2];
        int x = coords[4 * i + 3];
        int cell = b * GRIDC + z + y * NXD + x;
        atomicOr(map + cell, (i + 1) | (npts[i] << NPTS_SHIFT));
    } else if (i < M + K) {
        int r = sel[i - M];
        int b = coords[4 * r + 0];
        int z = coords[4 * r + 1];
        int y = coords[4 * r + 2];
        int x = coords[4 * r + 3];
        int cell = b * GRIDC + z + y * NXD + x;
        atomicOr(map + cell, SEL_FLAG);
    }
}

// LINEAR-store one-pass fill: block bid < SPATIAL_BLOCKS owns the 4KB output
// span [bid*1024, bid*1024+1024) floats == (frame b, channel c, 1024 cells).
// Consecutive blocks write consecutive addresses -> fill-like streaming.
// Tail blocks write the three meta maps (3 linear streams).
__global__ __launch_bounds__(256) void linear_fill_kernel(
        const float* __restrict__ feats,
        const int*   __restrict__ map,
        const float* __restrict__ zerobuf,
        float* __restrict__ out) {
    const int bid = blockIdx.x;
    const int t   = threadIdx.x;

    if (bid < SPATIAL_BLOCKS) {
        // bid = ((b*64 + c) * 256 + chunk)
        const int b     = bid >> 14;            // / (64*256)
        const int c     = (bid >> 8) & 63;
        const int chunk = bid & 255;
        const int cell0 = chunk * 1024 + t * 4; // cell within frame

        const i32x4 m4 = *reinterpret_cast<const i32x4*>(
            map + (size_t)b * GRIDC + cell0);
        const int rows[4] = {m4.x, m4.y, m4.z, m4.w};

        f32x4 v;
        #pragma unroll
        for (int j = 0; j < 4; ++j) {
            int m = rows[j];
            // branch-free: unselected cells read zerobuf[c] (L1 broadcast)
            const float* p = (m & SEL_FLAG)
                ? (feats + ((size_t)((m & ROW_MASK) - 1) << 6))
                : zerobuf;
            v[j] = p[c];
        }
        __builtin_nontemporal_store(
            v, reinterpret_cast<f32x4*>(out + (size_t)bid * 1024 + t * 4));
    } else {
        // meta: occ / dens / pnum, each [B][GRIDC], after the spatial region
        const int mid = bid - SPATIAL_BLOCKS;           // 0..1023
        const size_t cbase = (size_t)mid * 1024 + t * 4; // global cell id

        const i32x4 m4 = *reinterpret_cast<const i32x4*>(map + cbase);
        const int rows[4] = {m4.x, m4.y, m4.z, m4.w};

        const size_t spatial_elems = (size_t)BD * CD * GRIDC;
        const size_t map_elems     = (size_t)BD * GRIDC;
        float* __restrict__ occ  = out + spatial_elems;
        float* __restrict__ dens = occ + map_elems;
        float* __restrict__ pnum = dens + map_elems;

        f32x4 o, d, pn;
        #pragma unroll
        for (int j = 0; j < 4; ++j) {
            int m = rows[j];
            if (m != 0) {
                float n = (float)((m >> NPTS_SHIFT) & 63);
                o[j] = 1.0f;
                d[j] = n * (1.0f / 32.0f);
                pn[j] = n;
            } else {
                o[j] = 0.f; d[j] = 0.f; pn[j] = 0.f;
            }
        }
        __builtin_nontemporal_store(o,  reinterpret_cast<f32x4*>(occ  + cbase));
        __builtin_nontemporal_store(d,  reinterpret_cast<f32x4*>(dens + cbase));
        __builtin_nontemporal_store(pn, reinterpret_cast<f32x4*>(pnum + cbase));
    }
}

// ---------------- fallback path (used only if ws too small) ----------------

__global__ void scatter_meta_kernel(const int* __restrict__ coords,
                                    const int* __restrict__ npts,
                                    float* __restrict__ occ,
                                    float* __restrict__ dens,
                                    float* __restrict__ pnum,
                                    int M) {
    int i = blockIdx.x * blockDim.x + threadIdx.x;
    if (i >= M) return;
    int b = coords[4 * i + 0];
    int z = coords[4 * i + 1];
    int y = coords[4 * i + 2];
    int x = coords[4 * i + 3];
    int cell = b * GRIDC + z + y * NXD + x;
    float n = (float)npts[i];
    occ[cell]  = 1.0f;
    dens[cell] = n * (1.0f / 32.0f);
    pnum[cell] = n;
}

__global__ void scatter_spatial_kernel(const float* __restrict__ feats,
                                       const int* __restrict__ coords,
                                       const int* __restrict__ sel,
                                       float* __restrict__ spatial,
                                       int K) {
    int group = blockIdx.x * (blockDim.x >> 6) + (threadIdx.x >> 6);
    int c     = threadIdx.x & 63;
    if (group >= K) return;
    int row = sel[group];
    int b = coords[4 * row + 0];
    int z = coords[4 * row + 1];
    int y = coords[4 * row + 2];
    int x = coords[4 * row + 3];
    int cell = z + y * NXD + x;
    float v = feats[(size_t)row * CD + c];
    spatial[(size_t)b * ((size_t)CD * GRIDC) + (size_t)c * GRIDC + (size_t)cell] = v;
}

extern "C" void kernel_launch(void* const* d_in, const int* in_sizes, int n_in,
                              void* d_out, int out_size, void* d_ws, size_t ws_size,
                              hipStream_t stream) {
    const float* feats  = (const float*)d_in[0];  // [M, 64] f32
    const int*   coords = (const int*)d_in[1];    // [M, 4]  (b,z,y,x)
    const int*   npts   = (const int*)d_in[2];    // [M]
    const int*   sel    = (const int*)d_in[3];    // [K]

    const int M = in_sizes[2];
    const int K = in_sizes[3];

    float* out = (float*)d_out;
    const size_t map_bytes  = (size_t)BD * GRIDC * sizeof(int);  // 4 MB
    const size_t zero_bytes = CD * sizeof(float);                // 256 B

    if (ws_size >= map_bytes + zero_bytes) {
        int* map = (int*)d_ws;
        const float* zerobuf = (const float*)((char*)d_ws + map_bytes);
        (void)hipMemsetAsync(d_ws, 0, map_bytes + zero_bytes, stream);
        build_map_kernel<<<(M + K + 255) / 256, 256, 0, stream>>>(
            coords, sel, npts, map, M, K);
        linear_fill_kernel<<<SPATIAL_BLOCKS + META_BLOCKS, 256, 0, stream>>>(
            feats, map, zerobuf, out);
    } else {
        // fallback: memset + scatter
        size_t spatial_elems = (size_t)BD * CD * GRIDC;
        size_t map_elems     = (size_t)BD * GRIDC;
        float* occ  = out + spatial_elems;
        float* dens = occ + map_elems;
        float* pnum = dens + map_elems;
        (void)hipMemsetAsync(d_out, 0, (size_t)out_size * sizeof(float), stream);
        scatter_meta_kernel<<<(M + 255) / 256, 256, 0, stream>>>(
            coords, npts, occ, dens, pnum, M);
        scatter_spatial_kernel<<<(K + 3) / 4, 256, 0, stream>>>(
            feats, coords, sel, out, K);
    }
}